// Round 3
// baseline (1281.139 us; speedup 1.0000x reference)
//
#include <hip/hip_runtime.h>
#include <hip/hip_bf16.h>

// CFConv, round 2.
//   out = segment_sum( (x@Wl+bl)[col] * (relu(rbf@W1+b1)@W2+b2), row )
// Structure:
//   1. node_linear_mfma: h = bf16(x@Wl+bl)           (MFMA, B-frags in regs)
//   2. hist/scan/scatter: counting-sort edges by dst -> perm, row_ptr (CSR)
//   3. cfconv_fused_kernel: persistent blocks; each block owns 8 dst nodes =
//      one contiguous sorted-edge range. Per 64-edge sub-tile: gather rbf via
//      perm -> MFMA GEMM1 -> relu -> LDS -> MFMA GEMM2 -> modulate by gathered
//      h -> ds_add_f32 into 8x128 LDS out-tile. Plain-store the 8 rows.
//      ZERO global atomics, no msg materialization, no out memset.

#define N_NODES 40000
#define N_EDGES 640000
#define IN_CH 128
#define OUT_CH 128
#define NUM_RBF 64

#define TILE_M 64
#define RBF_STR 72   // ushorts
#define T_STR 136    // ushorts
#define W1_STR 72
#define W2_STR 136

#define NPB 8                       // dst nodes per block-group
#define NGROUPS (N_NODES / NPB)     // 5000

typedef __attribute__((ext_vector_type(8))) short bf16x8;
typedef __attribute__((ext_vector_type(16))) float f32x16;

__device__ __forceinline__ unsigned short f2bf(float f) {
  unsigned u = __float_as_uint(f);
  return (unsigned short)((u + 0x7FFFu + ((u >> 16) & 1u)) >> 16);
}
__device__ __forceinline__ float bf2f(unsigned short s) {
  return __uint_as_float(((unsigned)s) << 16);
}

// ---------------------------------------------------------------------------
// h = bf16(x @ Wl + bl)
// ---------------------------------------------------------------------------
__global__ __launch_bounds__(256) void node_linear_mfma(
    const float* __restrict__ x, const float* __restrict__ Wl,
    const float* __restrict__ bl, unsigned short* __restrict__ hbf) {
  __shared__ __align__(16) char pool[IN_CH * W2_STR * 2];  // 34816 B
  const int t = threadIdx.x;
  const int lane = t & 63;
  const int l31 = lane & 31;
  const int lhalf = lane >> 5;
  const int wv = t >> 6;

  {
    unsigned short* sWT = (unsigned short*)pool;
    const int k2 = t >> 1;
    const int d0 = (t & 1) * 64;
#pragma unroll
    for (int i = 0; i < 16; ++i) {
      float4 v = *(const float4*)(Wl + k2 * OUT_CH + d0 + 4 * i);
      sWT[(d0 + 4 * i + 0) * W2_STR + k2] = f2bf(v.x);
      sWT[(d0 + 4 * i + 1) * W2_STR + k2] = f2bf(v.y);
      sWT[(d0 + 4 * i + 2) * W2_STR + k2] = f2bf(v.z);
      sWT[(d0 + 4 * i + 3) * W2_STR + k2] = f2bf(v.w);
    }
  }
  __syncthreads();
  const int nbase = wv * 32 + l31;
  bf16x8 BW[8];
  {
    const unsigned short* sWT = (const unsigned short*)pool;
#pragma unroll
    for (int kk = 0; kk < 8; ++kk)
      BW[kk] = *(const bf16x8*)&sWT[nbase * W2_STR + kk * 16 + lhalf * 8];
  }
  const float blv = bl[nbase];
  __syncthreads();

  const int rbase = blockIdx.x * TILE_M;
  unsigned short* sX = (unsigned short*)pool;
  {
    const int m = t >> 2;
    const int c0 = (t & 3) * 32;
    const float* src = x + (size_t)(rbase + m) * IN_CH + c0;
#pragma unroll
    for (int i = 0; i < 8; ++i) {
      float4 v = *(const float4*)(src + 4 * i);
      ushort4 p;
      p.x = f2bf(v.x); p.y = f2bf(v.y); p.z = f2bf(v.z); p.w = f2bf(v.w);
      *(ushort4*)&sX[m * T_STR + c0 + 4 * i] = p;
    }
  }
  __syncthreads();
#pragma unroll
  for (int mt = 0; mt < 2; ++mt) {
    f32x16 acc = {0.f, 0.f, 0.f, 0.f, 0.f, 0.f, 0.f, 0.f,
                  0.f, 0.f, 0.f, 0.f, 0.f, 0.f, 0.f, 0.f};
#pragma unroll
    for (int kk = 0; kk < 8; ++kk) {
      bf16x8 A = *(const bf16x8*)&sX[(mt * 32 + l31) * T_STR + kk * 16 + lhalf * 8];
      acc = __builtin_amdgcn_mfma_f32_32x32x16_bf16(A, BW[kk], acc, 0, 0, 0);
    }
#pragma unroll
    for (int r = 0; r < 16; ++r) {
      const int rowm = mt * 32 + (r & 3) + 8 * (r >> 2) + 4 * lhalf;
      hbf[(size_t)(rbase + rowm) * OUT_CH + nbase] = f2bf(acc[r] + blv);
    }
  }
}

// ---------------------------------------------------------------------------
// counting sort by dst
// ---------------------------------------------------------------------------
__global__ void hist_kernel(const int* __restrict__ rowI, int* __restrict__ count) {
  int e = blockIdx.x * 256 + threadIdx.x;
  if (e < N_EDGES) atomicAdd(&count[rowI[e]], 1);
}

__global__ __launch_bounds__(1024) void scan_kernel(const int* __restrict__ count,
                                                    int* __restrict__ cursor,
                                                    int* __restrict__ row_ptr) {
  __shared__ int sSum[1024];
  const int t = threadIdx.x;
  const int per = (N_NODES + 1023) / 1024;  // 40
  const int base = t * per;
  int s = 0;
  for (int i = 0; i < per; ++i) {
    int idx = base + i;
    if (idx < N_NODES) s += count[idx];
  }
  sSum[t] = s;
  __syncthreads();
  for (int off = 1; off < 1024; off <<= 1) {
    int v = (t >= off) ? sSum[t - off] : 0;
    __syncthreads();
    sSum[t] += v;
    __syncthreads();
  }
  int run = (t == 0) ? 0 : sSum[t - 1];
  for (int i = 0; i < per; ++i) {
    int idx = base + i;
    if (idx < N_NODES) {
      cursor[idx] = run;
      row_ptr[idx] = run;
      run += count[idx];
    }
  }
  if (t == 0) row_ptr[N_NODES] = N_EDGES;
}

__global__ void scatter_kernel(const int* __restrict__ rowI, int* __restrict__ cursor,
                               int* __restrict__ perm) {
  int e = blockIdx.x * 256 + threadIdx.x;
  if (e < N_EDGES) {
    int pos = atomicAdd(&cursor[rowI[e]], 1);
    perm[pos] = e;
  }
}

// ---------------------------------------------------------------------------
// fused filter+modulate+segment-sum over dst-sorted edges; no global atomics
// ---------------------------------------------------------------------------
__global__ __launch_bounds__(256, 3) void cfconv_fused_kernel(
    const int* __restrict__ eidx, const float* __restrict__ rbf,
    const float* __restrict__ W1, const float* __restrict__ b1,
    const float* __restrict__ W2, const float* __restrict__ b2,
    const unsigned short* __restrict__ hbf, const int* __restrict__ perm,
    const int* __restrict__ row_ptr, float* __restrict__ out) {
  __shared__ __align__(16) char pool[IN_CH * W2_STR * 2];  // 34816 B (aliased)
  __shared__ float sOut[NPB * OUT_CH];                     // 4096 B
  __shared__ int sLoc[TILE_M], sSrc[TILE_M], sMask[TILE_M];

  unsigned short* sT = (unsigned short*)pool;                     // 17408 B
  unsigned short* sRbf = (unsigned short*)(pool + TILE_M * T_STR * 2);  // 9216 B

  const int t = threadIdx.x;
  const int lane = t & 63;
  const int l31 = lane & 31;
  const int lhalf = lane >> 5;
  const int wv = t >> 6;
  const int nbase = wv * 32 + l31;

  // ---- stage W1 -> B1 frags, then W2 -> B2 frags (pool reused) ----
  {
    unsigned short* sW1T = (unsigned short*)pool;
    const int k = t >> 2;
    const int c0 = (t & 3) * 32;
#pragma unroll
    for (int i = 0; i < 8; ++i) {
      float4 v = *(const float4*)(W1 + k * OUT_CH + c0 + 4 * i);
      sW1T[(c0 + 4 * i + 0) * W1_STR + k] = f2bf(v.x);
      sW1T[(c0 + 4 * i + 1) * W1_STR + k] = f2bf(v.y);
      sW1T[(c0 + 4 * i + 2) * W1_STR + k] = f2bf(v.z);
      sW1T[(c0 + 4 * i + 3) * W1_STR + k] = f2bf(v.w);
    }
  }
  __syncthreads();
  bf16x8 B1[4];
  {
    const unsigned short* sW1T = (const unsigned short*)pool;
#pragma unroll
    for (int kk = 0; kk < 4; ++kk)
      B1[kk] = *(const bf16x8*)&sW1T[nbase * W1_STR + kk * 16 + lhalf * 8];
  }
  __syncthreads();
  {
    unsigned short* sW2T = (unsigned short*)pool;
    const int k2 = t >> 1;
    const int d0 = (t & 1) * 64;
#pragma unroll
    for (int i = 0; i < 16; ++i) {
      float4 v = *(const float4*)(W2 + k2 * OUT_CH + d0 + 4 * i);
      sW2T[(d0 + 4 * i + 0) * W2_STR + k2] = f2bf(v.x);
      sW2T[(d0 + 4 * i + 1) * W2_STR + k2] = f2bf(v.y);
      sW2T[(d0 + 4 * i + 2) * W2_STR + k2] = f2bf(v.z);
      sW2T[(d0 + 4 * i + 3) * W2_STR + k2] = f2bf(v.w);
    }
  }
  __syncthreads();
  bf16x8 B2[8];
  {
    const unsigned short* sW2T = (const unsigned short*)pool;
#pragma unroll
    for (int kk = 0; kk < 8; ++kk)
      B2[kk] = *(const bf16x8*)&sW2T[nbase * W2_STR + kk * 16 + lhalf * 8];
  }
  const float b1v = b1[nbase];
  const float b2v = b2[nbase];

  const int* rowI = eidx;
  const int* colI = eidx + N_EDGES;

  for (int g = blockIdx.x; g < NGROUPS; g += gridDim.x) {
    const int n0 = g * NPB;
    const int ebeg = row_ptr[n0];
    const int eend = row_ptr[n0 + NPB];

    // zero out-tile (each thread zeroes the same cells it later flushes)
    for (int i = t; i < NPB * OUT_CH; i += 256) sOut[i] = 0.f;

    const int nsub = (eend - ebeg + TILE_M - 1) >> 6;
    for (int st = 0; st < nsub; ++st) {
      const int ebase = ebeg + st * TILE_M;
      __syncthreads();  // (a) prev sT reads / sOut zero visible before reuse

      // ---- stage rbf (perm gather) + per-edge meta ----
      {
        const int m = t >> 2;
        int em = ebase + m;
        if (em >= eend) em = eend - 1;
        const int pe = perm[em];
        const int kq = (t & 3) * 16;
        const float* src = rbf + (size_t)pe * NUM_RBF + kq;
#pragma unroll
        for (int i = 0; i < 4; ++i) {
          float4 v = *(const float4*)(src + 4 * i);
          ushort4 p;
          p.x = f2bf(v.x); p.y = f2bf(v.y); p.z = f2bf(v.z); p.w = f2bf(v.w);
          *(ushort4*)&sRbf[m * RBF_STR + kq + 4 * i] = p;
        }
        if (t < TILE_M) {
          const int e2 = ebase + t;
          const int v = (e2 < eend) ? 1 : 0;
          const int pe2 = perm[v ? e2 : (eend - 1)];
          sLoc[t] = rowI[pe2] - n0;  // in [0, NPB)
          sSrc[t] = colI[pe2];
          sMask[t] = v;
        }
      }
      __syncthreads();  // (b)

      // ---- GEMM1: sT = bf16(relu(rbf @ W1 + b1)) ----
#pragma unroll
      for (int mt = 0; mt < 2; ++mt) {
        f32x16 acc = {0.f, 0.f, 0.f, 0.f, 0.f, 0.f, 0.f, 0.f,
                      0.f, 0.f, 0.f, 0.f, 0.f, 0.f, 0.f, 0.f};
#pragma unroll
        for (int kk = 0; kk < 4; ++kk) {
          bf16x8 A = *(const bf16x8*)&sRbf[(mt * 32 + l31) * RBF_STR + kk * 16 + lhalf * 8];
          acc = __builtin_amdgcn_mfma_f32_32x32x16_bf16(A, B1[kk], acc, 0, 0, 0);
        }
#pragma unroll
        for (int r = 0; r < 16; ++r) {
          const int rowm = (r & 3) + 8 * (r >> 2) + 4 * lhalf;
          float v = acc[r] + b1v;
          v = v > 0.f ? v : 0.f;
          sT[(mt * 32 + rowm) * T_STR + nbase] = f2bf(v);
        }
      }
      __syncthreads();  // (c)

      // ---- h gather (masked), overlaps GEMM2 ----
      float hv[2][16];
#pragma unroll
      for (int mt = 0; mt < 2; ++mt)
#pragma unroll
        for (int r = 0; r < 16; ++r) {
          const int rowm = mt * 32 + (r & 3) + 8 * (r >> 2) + 4 * lhalf;
          hv[mt][r] = sMask[rowm]
                          ? bf2f(hbf[(size_t)sSrc[rowm] * OUT_CH + nbase])
                          : 0.f;
        }

      // ---- GEMM2 + LDS accumulate ----
#pragma unroll
      for (int mt = 0; mt < 2; ++mt) {
        f32x16 acc = {0.f, 0.f, 0.f, 0.f, 0.f, 0.f, 0.f, 0.f,
                      0.f, 0.f, 0.f, 0.f, 0.f, 0.f, 0.f, 0.f};
#pragma unroll
        for (int kk = 0; kk < 8; ++kk) {
          bf16x8 A = *(const bf16x8*)&sT[(mt * 32 + l31) * T_STR + kk * 16 + lhalf * 8];
          acc = __builtin_amdgcn_mfma_f32_32x32x16_bf16(A, B2[kk], acc, 0, 0, 0);
        }
#pragma unroll
        for (int r = 0; r < 16; ++r) {
          const int rowm = mt * 32 + (r & 3) + 8 * (r >> 2) + 4 * lhalf;
          atomicAdd(&sOut[sLoc[rowm] * OUT_CH + nbase],
                    hv[mt][r] * (acc[r] + b2v));
        }
      }
    }
    __syncthreads();  // (d) all ds_adds done

    // ---- flush 8 node rows, plain stores ----
    for (int i = t; i < NPB * OUT_CH; i += 256)
      out[(size_t)n0 * OUT_CH + i] = sOut[i];
    // no barrier needed: re-zero hits only this thread's own cells
  }
}

extern "C" void kernel_launch(void* const* d_in, const int* in_sizes, int n_in,
                              void* d_out, int out_size, void* d_ws, size_t ws_size,
                              hipStream_t stream) {
  const float* x    = (const float*)d_in[0];
  const int*   eidx = (const int*)d_in[1];
  const float* rbf  = (const float*)d_in[2];
  const float* W1   = (const float*)d_in[3];
  const float* b1   = (const float*)d_in[4];
  const float* W2   = (const float*)d_in[5];
  const float* b2   = (const float*)d_in[6];
  const float* Wl   = (const float*)d_in[7];
  const float* bl   = (const float*)d_in[8];
  float* out = (float*)d_out;

  char* ws = (char*)d_ws;
  unsigned short* hbf = (unsigned short*)ws;     // 10,240,000 B
  int* perm    = (int*)(ws + 10240000);          //  2,560,000 B
  int* count   = (int*)(ws + 12800000);          //    160,000 B
  int* cursor  = (int*)(ws + 12960000);          //    160,000 B
  int* row_ptr = (int*)(ws + 13120000);          //    160,004 B

  hipMemsetAsync(count, 0, sizeof(int) * N_NODES, stream);
  node_linear_mfma<<<N_NODES / TILE_M, 256, 0, stream>>>(x, Wl, bl, hbf);
  hist_kernel<<<(N_EDGES + 255) / 256, 256, 0, stream>>>(eidx, count);
  scan_kernel<<<1, 1024, 0, stream>>>(count, cursor, row_ptr);
  scatter_kernel<<<(N_EDGES + 255) / 256, 256, 0, stream>>>(eidx, cursor, perm);
  cfconv_fused_kernel<<<1024, 256, 0, stream>>>(eidx, rbf, W1, b1, W2, b2, hbf,
                                                perm, row_ptr, out);
}

// Round 4
// 572.036 us; speedup vs baseline: 2.2396x; 2.2396x over previous
//
#include <hip/hip_runtime.h>
#include <hip/hip_bf16.h>

// CFConv, round 3. Two-pass streaming structure:
//   Pass A (natural edge order): msg_sorted[spos[e]] = bf16( h[col[e]] *
//            (relu(rbf[e]@W1+b1)@W2+b2) )   -- MFMA, no atomics
//   Pass B: out[n] = sum of contiguous msg_sorted rows [row_ptr[n],row_ptr[n+1])
//            -- one wave per node, coalesced reads, registers, plain store
// Counting sort (hist/scan/scatter) provides spos + row_ptr.
// Fallback: if ws_size too small for the 164MB msg buffer, pass A does
// global atomicAdd directly (round-0 style).

#define N_NODES 40000
#define N_EDGES 640000
#define IN_CH 128
#define OUT_CH 128
#define NUM_RBF 64

#define TILE_M 64
#define NTILES (N_EDGES / TILE_M)  // 10000 exact
#define RBF_STR 72   // ushorts
#define T_STR 136    // ushorts
#define W1_STR 72
#define W2_STR 136

typedef __attribute__((ext_vector_type(8))) short bf16x8;
typedef __attribute__((ext_vector_type(16))) float f32x16;

__device__ __forceinline__ unsigned short f2bf(float f) {
  unsigned u = __float_as_uint(f);
  return (unsigned short)((u + 0x7FFFu + ((u >> 16) & 1u)) >> 16);
}
__device__ __forceinline__ float bf2f(unsigned short s) {
  return __uint_as_float(((unsigned)s) << 16);
}

// ---------------------------------------------------------------------------
// h = bf16(x @ Wl + bl)
// ---------------------------------------------------------------------------
__global__ __launch_bounds__(256) void node_linear_mfma(
    const float* __restrict__ x, const float* __restrict__ Wl,
    const float* __restrict__ bl, unsigned short* __restrict__ hbf) {
  __shared__ __align__(16) char pool[IN_CH * W2_STR * 2];  // 34816 B
  const int t = threadIdx.x;
  const int lane = t & 63;
  const int l31 = lane & 31;
  const int lhalf = lane >> 5;
  const int wv = t >> 6;

  {
    unsigned short* sWT = (unsigned short*)pool;
    const int k2 = t >> 1;
    const int d0 = (t & 1) * 64;
#pragma unroll
    for (int i = 0; i < 16; ++i) {
      float4 v = *(const float4*)(Wl + k2 * OUT_CH + d0 + 4 * i);
      sWT[(d0 + 4 * i + 0) * W2_STR + k2] = f2bf(v.x);
      sWT[(d0 + 4 * i + 1) * W2_STR + k2] = f2bf(v.y);
      sWT[(d0 + 4 * i + 2) * W2_STR + k2] = f2bf(v.z);
      sWT[(d0 + 4 * i + 3) * W2_STR + k2] = f2bf(v.w);
    }
  }
  __syncthreads();
  const int nbase = wv * 32 + l31;
  bf16x8 BW[8];
  {
    const unsigned short* sWT = (const unsigned short*)pool;
#pragma unroll
    for (int kk = 0; kk < 8; ++kk)
      BW[kk] = *(const bf16x8*)&sWT[nbase * W2_STR + kk * 16 + lhalf * 8];
  }
  const float blv = bl[nbase];
  __syncthreads();

  const int rbase = blockIdx.x * TILE_M;
  unsigned short* sX = (unsigned short*)pool;
  {
    const int m = t >> 2;
    const int c0 = (t & 3) * 32;
    const float* src = x + (size_t)(rbase + m) * IN_CH + c0;
#pragma unroll
    for (int i = 0; i < 8; ++i) {
      float4 v = *(const float4*)(src + 4 * i);
      ushort4 p;
      p.x = f2bf(v.x); p.y = f2bf(v.y); p.z = f2bf(v.z); p.w = f2bf(v.w);
      *(ushort4*)&sX[m * T_STR + c0 + 4 * i] = p;
    }
  }
  __syncthreads();
#pragma unroll
  for (int mt = 0; mt < 2; ++mt) {
    f32x16 acc = {0.f, 0.f, 0.f, 0.f, 0.f, 0.f, 0.f, 0.f,
                  0.f, 0.f, 0.f, 0.f, 0.f, 0.f, 0.f, 0.f};
#pragma unroll
    for (int kk = 0; kk < 8; ++kk) {
      bf16x8 A = *(const bf16x8*)&sX[(mt * 32 + l31) * T_STR + kk * 16 + lhalf * 8];
      acc = __builtin_amdgcn_mfma_f32_32x32x16_bf16(A, BW[kk], acc, 0, 0, 0);
    }
#pragma unroll
    for (int r = 0; r < 16; ++r) {
      const int rowm = mt * 32 + (r & 3) + 8 * (r >> 2) + 4 * lhalf;
      hbf[(size_t)(rbase + rowm) * OUT_CH + nbase] = f2bf(acc[r] + blv);
    }
  }
}

// ---------------------------------------------------------------------------
// counting sort by dst -> spos (per-edge sorted position), row_ptr
// ---------------------------------------------------------------------------
__global__ void hist_kernel(const int* __restrict__ rowI, int* __restrict__ count) {
  int e = blockIdx.x * 256 + threadIdx.x;
  if (e < N_EDGES) atomicAdd(&count[rowI[e]], 1);
}

__global__ __launch_bounds__(1024) void scan_kernel(const int* __restrict__ count,
                                                    int* __restrict__ cursor,
                                                    int* __restrict__ row_ptr) {
  __shared__ int sSum[1024];
  const int t = threadIdx.x;
  const int per = (N_NODES + 1023) / 1024;  // 40
  const int base = t * per;
  int s = 0;
  for (int i = 0; i < per; ++i) {
    int idx = base + i;
    if (idx < N_NODES) s += count[idx];
  }
  sSum[t] = s;
  __syncthreads();
  for (int off = 1; off < 1024; off <<= 1) {
    int v = (t >= off) ? sSum[t - off] : 0;
    __syncthreads();
    sSum[t] += v;
    __syncthreads();
  }
  int run = (t == 0) ? 0 : sSum[t - 1];
  for (int i = 0; i < per; ++i) {
    int idx = base + i;
    if (idx < N_NODES) {
      cursor[idx] = run;
      row_ptr[idx] = run;
      run += count[idx];
    }
  }
  if (t == 0) row_ptr[N_NODES] = N_EDGES;
}

__global__ void scatter_kernel(const int* __restrict__ rowI, int* __restrict__ cursor,
                               int* __restrict__ spos) {
  int e = blockIdx.x * 256 + threadIdx.x;
  if (e < N_EDGES) spos[e] = atomicAdd(&cursor[rowI[e]], 1);
}

// ---------------------------------------------------------------------------
// Pass A: filter + modulate, natural edge order.
//   ATOMIC=false: scatter-store bf16 msg rows to sorted positions (aux=spos)
//   ATOMIC=true : atomicAdd fp32 into out (aux=rowI), round-0 fallback
// ---------------------------------------------------------------------------
template <bool ATOMIC>
__global__ __launch_bounds__(256, 4) void edge_filter_kernel(
    const int* __restrict__ eidx, const float* __restrict__ rbf,
    const float* __restrict__ W1, const float* __restrict__ b1,
    const float* __restrict__ W2, const float* __restrict__ b2,
    const unsigned short* __restrict__ hbf, const int* __restrict__ aux,
    unsigned short* __restrict__ msg, float* __restrict__ outp) {
  __shared__ __align__(16) char pool[IN_CH * W2_STR * 2];  // 34816 B
  __shared__ int sCol[TILE_M], sAux[TILE_M];

  unsigned short* sT = (unsigned short*)pool;                       // 17408 B
  unsigned short* sRbf = (unsigned short*)(pool + TILE_M * T_STR * 2);  // 9216 B
  unsigned short* sMsg = (unsigned short*)(pool + TILE_M * T_STR * 2);  // 17408 B (after GEMM1)

  const int t = threadIdx.x;
  const int lane = t & 63;
  const int l31 = lane & 31;
  const int lhalf = lane >> 5;
  const int wv = t >> 6;
  const int nbase = wv * 32 + l31;

  // ---- weight fragments (pool reused twice) ----
  {
    unsigned short* sW1T = (unsigned short*)pool;
    const int k = t >> 2;
    const int c0 = (t & 3) * 32;
#pragma unroll
    for (int i = 0; i < 8; ++i) {
      float4 v = *(const float4*)(W1 + k * OUT_CH + c0 + 4 * i);
      sW1T[(c0 + 4 * i + 0) * W1_STR + k] = f2bf(v.x);
      sW1T[(c0 + 4 * i + 1) * W1_STR + k] = f2bf(v.y);
      sW1T[(c0 + 4 * i + 2) * W1_STR + k] = f2bf(v.z);
      sW1T[(c0 + 4 * i + 3) * W1_STR + k] = f2bf(v.w);
    }
  }
  __syncthreads();
  bf16x8 B1[4];
  {
    const unsigned short* sW1T = (const unsigned short*)pool;
#pragma unroll
    for (int kk = 0; kk < 4; ++kk)
      B1[kk] = *(const bf16x8*)&sW1T[nbase * W1_STR + kk * 16 + lhalf * 8];
  }
  __syncthreads();
  {
    unsigned short* sW2T = (unsigned short*)pool;
    const int k2 = t >> 1;
    const int d0 = (t & 1) * 64;
#pragma unroll
    for (int i = 0; i < 16; ++i) {
      float4 v = *(const float4*)(W2 + k2 * OUT_CH + d0 + 4 * i);
      sW2T[(d0 + 4 * i + 0) * W2_STR + k2] = f2bf(v.x);
      sW2T[(d0 + 4 * i + 1) * W2_STR + k2] = f2bf(v.y);
      sW2T[(d0 + 4 * i + 2) * W2_STR + k2] = f2bf(v.z);
      sW2T[(d0 + 4 * i + 3) * W2_STR + k2] = f2bf(v.w);
    }
  }
  __syncthreads();
  bf16x8 B2[8];
  {
    const unsigned short* sW2T = (const unsigned short*)pool;
#pragma unroll
    for (int kk = 0; kk < 8; ++kk)
      B2[kk] = *(const bf16x8*)&sW2T[nbase * W2_STR + kk * 16 + lhalf * 8];
  }
  const float b1v = b1[nbase];
  const float b2v = b2[nbase];

  const int* colI = eidx + N_EDGES;

  for (int tile = blockIdx.x; tile < NTILES; tile += gridDim.x) {
    const int ebase = tile * TILE_M;
    __syncthreads();  // (a) prev tile's reads of sMsg/sCol/sAux complete

    // ---- stage rbf tile (bf16, streaming-coalesced) + col + aux ----
    {
      const int m = t >> 2;
      const int kq = (t & 3) * 16;
      const float* src = rbf + (size_t)(ebase + m) * NUM_RBF + kq;
#pragma unroll
      for (int i = 0; i < 4; ++i) {
        float4 v = *(const float4*)(src + 4 * i);
        ushort4 p;
        p.x = f2bf(v.x); p.y = f2bf(v.y); p.z = f2bf(v.z); p.w = f2bf(v.w);
        *(ushort4*)&sRbf[m * RBF_STR + kq + 4 * i] = p;
      }
      if (t < TILE_M) sCol[t] = colI[ebase + t];
      else if (t < 2 * TILE_M) sAux[t - TILE_M] = aux[ebase + t - TILE_M];
    }
    __syncthreads();  // (b)

    // ---- GEMM1: sT = bf16(relu(rbf @ W1 + b1)) ----
#pragma unroll
    for (int mt = 0; mt < 2; ++mt) {
      f32x16 acc = {0.f, 0.f, 0.f, 0.f, 0.f, 0.f, 0.f, 0.f,
                    0.f, 0.f, 0.f, 0.f, 0.f, 0.f, 0.f, 0.f};
#pragma unroll
      for (int kk = 0; kk < 4; ++kk) {
        bf16x8 A = *(const bf16x8*)&sRbf[(mt * 32 + l31) * RBF_STR + kk * 16 + lhalf * 8];
        acc = __builtin_amdgcn_mfma_f32_32x32x16_bf16(A, B1[kk], acc, 0, 0, 0);
      }
#pragma unroll
      for (int r = 0; r < 16; ++r) {
        const int rowm = (r & 3) + 8 * (r >> 2) + 4 * lhalf;
        float v = acc[r] + b1v;
        v = v > 0.f ? v : 0.f;
        sT[(mt * 32 + rowm) * T_STR + nbase] = f2bf(v);
      }
    }
    __syncthreads();  // (c) -- sRbf dead from here; sMsg may reuse its space

    // ---- h gather (overlaps GEMM2) ----
    float hv[2][16];
#pragma unroll
    for (int mt = 0; mt < 2; ++mt)
#pragma unroll
      for (int r = 0; r < 16; ++r) {
        const int rowm = mt * 32 + (r & 3) + 8 * (r >> 2) + 4 * lhalf;
        hv[mt][r] = bf2f(hbf[(size_t)sCol[rowm] * OUT_CH + nbase]);
      }

    // ---- GEMM2 + modulate ----
#pragma unroll
    for (int mt = 0; mt < 2; ++mt) {
      f32x16 acc = {0.f, 0.f, 0.f, 0.f, 0.f, 0.f, 0.f, 0.f,
                    0.f, 0.f, 0.f, 0.f, 0.f, 0.f, 0.f, 0.f};
#pragma unroll
      for (int kk = 0; kk < 8; ++kk) {
        bf16x8 A = *(const bf16x8*)&sT[(mt * 32 + l31) * T_STR + kk * 16 + lhalf * 8];
        acc = __builtin_amdgcn_mfma_f32_32x32x16_bf16(A, B2[kk], acc, 0, 0, 0);
      }
#pragma unroll
      for (int r = 0; r < 16; ++r) {
        const int rowm = mt * 32 + (r & 3) + 8 * (r >> 2) + 4 * lhalf;
        const float m = hv[mt][r] * (acc[r] + b2v);
        if (ATOMIC) {
          atomicAdd(&outp[(size_t)sAux[rowm] * OUT_CH + nbase], m);
        } else {
          sMsg[rowm * T_STR + nbase] = f2bf(m);
        }
      }
    }

    if (!ATOMIC) {
      __syncthreads();  // (d) sMsg complete
      // scatter-store rows to sorted positions; 16B chunks, 4 threads/row
      const int m = t >> 2;
      unsigned short* dst = msg + (size_t)sAux[m] * OUT_CH;
#pragma unroll
      for (int i = 0; i < 4; ++i) {
        const int j = ((t & 3) * 4 + i) * 8;  // ushort offset, 16B chunk
        *(ushort4*)(dst + j) = *(const ushort4*)&sMsg[m * T_STR + j];
        *(ushort4*)(dst + j + 4) = *(const ushort4*)&sMsg[m * T_STR + j + 4];
      }
    }
  }
}

// ---------------------------------------------------------------------------
// Pass B: per-node contiguous segment reduce. One wave per node.
// ---------------------------------------------------------------------------
__global__ __launch_bounds__(256) void segment_reduce_kernel(
    const unsigned short* __restrict__ msg, const int* __restrict__ row_ptr,
    float* __restrict__ out) {
  const int t = threadIdx.x;
  const int wv = t >> 6;
  const int lane = t & 63;
  const int n = blockIdx.x * 4 + wv;
  const int ebeg = row_ptr[n];
  const int eend = row_ptr[n + 1];
  const unsigned* p = (const unsigned*)msg;  // row = 64 uints (128 bf16)

  float a0 = 0.f, a1 = 0.f;
  int e = ebeg;
  for (; e + 4 <= eend; e += 4) {
    unsigned v0 = p[(size_t)(e + 0) * 64 + lane];
    unsigned v1 = p[(size_t)(e + 1) * 64 + lane];
    unsigned v2 = p[(size_t)(e + 2) * 64 + lane];
    unsigned v3 = p[(size_t)(e + 3) * 64 + lane];
    a0 += bf2f((unsigned short)(v0 & 0xffff)) + bf2f((unsigned short)(v1 & 0xffff)) +
          bf2f((unsigned short)(v2 & 0xffff)) + bf2f((unsigned short)(v3 & 0xffff));
    a1 += bf2f((unsigned short)(v0 >> 16)) + bf2f((unsigned short)(v1 >> 16)) +
          bf2f((unsigned short)(v2 >> 16)) + bf2f((unsigned short)(v3 >> 16));
  }
  for (; e < eend; ++e) {
    unsigned v = p[(size_t)e * 64 + lane];
    a0 += bf2f((unsigned short)(v & 0xffff));
    a1 += bf2f((unsigned short)(v >> 16));
  }
  float2 r;
  r.x = a0;
  r.y = a1;
  *(float2*)&out[(size_t)n * OUT_CH + lane * 2] = r;
}

// ---------------------------------------------------------------------------
extern "C" void kernel_launch(void* const* d_in, const int* in_sizes, int n_in,
                              void* d_out, int out_size, void* d_ws, size_t ws_size,
                              hipStream_t stream) {
  const float* x    = (const float*)d_in[0];
  const int*   eidx = (const int*)d_in[1];
  const float* rbf  = (const float*)d_in[2];
  const float* W1   = (const float*)d_in[3];
  const float* b1   = (const float*)d_in[4];
  const float* W2   = (const float*)d_in[5];
  const float* b2   = (const float*)d_in[6];
  const float* Wl   = (const float*)d_in[7];
  const float* bl   = (const float*)d_in[8];
  float* out = (float*)d_out;

  char* ws = (char*)d_ws;
  // layout: hbf | msg | spos | count | cursor | row_ptr
  const size_t HBF_B = (size_t)N_NODES * OUT_CH * 2;       // 10,240,000
  const size_t MSG_B = (size_t)N_EDGES * OUT_CH * 2;       // 163,840,000
  const size_t SPOS_B = (size_t)N_EDGES * 4;               //   2,560,000
  const size_t CNT_B = (size_t)N_NODES * 4;                //     160,000
  const size_t need = HBF_B + MSG_B + SPOS_B + 3 * CNT_B + 64;

  unsigned short* hbf = (unsigned short*)ws;
  unsigned short* msg = (unsigned short*)(ws + HBF_B);
  int* spos    = (int*)(ws + HBF_B + MSG_B);
  int* count   = (int*)(ws + HBF_B + MSG_B + SPOS_B);
  int* cursor  = (int*)(ws + HBF_B + MSG_B + SPOS_B + CNT_B);
  int* row_ptr = (int*)(ws + HBF_B + MSG_B + SPOS_B + 2 * CNT_B);

  node_linear_mfma<<<N_NODES / TILE_M, 256, 0, stream>>>(x, Wl, bl, hbf);

  if (ws_size >= need) {
    hipMemsetAsync(count, 0, CNT_B, stream);
    hist_kernel<<<(N_EDGES + 255) / 256, 256, 0, stream>>>(eidx, count);
    scan_kernel<<<1, 1024, 0, stream>>>(count, cursor, row_ptr);
    scatter_kernel<<<(N_EDGES + 255) / 256, 256, 0, stream>>>(eidx, cursor, spos);
    edge_filter_kernel<false><<<1024, 256, 0, stream>>>(
        eidx, rbf, W1, b1, W2, b2, hbf, spos, msg, nullptr);
    segment_reduce_kernel<<<N_NODES / 4, 256, 0, stream>>>(msg, row_ptr, out);
  } else {
    // fallback: direct atomics (round-0 structure), aux = dst row indices
    hipMemsetAsync(out, 0, (size_t)N_NODES * OUT_CH * sizeof(float), stream);
    edge_filter_kernel<true><<<1024, 256, 0, stream>>>(
        eidx, rbf, W1, b1, W2, b2, hbf, eidx /*rowI*/, nullptr, out);
  }
}

// Round 5
// 438.453 us; speedup vs baseline: 2.9220x; 1.3047x over previous
//
#include <hip/hip_runtime.h>
#include <hip/hip_bf16.h>

// CFConv, round 4. Two-pass streaming (round-3 structure) with:
//  - edge kernel: h-gather restructured from 32x scalar ushort gathers/thread
//    to cooperative 16B-wide staging into LDS (sHv), epilogue reads via
//    ds_read_u16 (HV_STR=136 -> disjoint bank halves, conflict-free)
//  - hierarchical coalesced scan (3 tiny kernels) replacing 1-block scan
//  - edge grid 2500 blocks (shorter tail)

#define N_NODES 40000
#define N_EDGES 640000
#define IN_CH 128
#define OUT_CH 128
#define NUM_RBF 64

#define TILE_M 64
#define NTILES (N_EDGES / TILE_M)  // 10000 exact
#define RBF_STR 72   // ushorts
#define T_STR 136    // ushorts
#define HV_STR 136   // ushorts
#define W1_STR 72
#define W2_STR 136
#define NSCB ((N_NODES + 255) / 256)  // 157 scan blocks

typedef __attribute__((ext_vector_type(8))) short bf16x8;
typedef __attribute__((ext_vector_type(16))) float f32x16;

__device__ __forceinline__ unsigned short f2bf(float f) {
  unsigned u = __float_as_uint(f);
  return (unsigned short)((u + 0x7FFFu + ((u >> 16) & 1u)) >> 16);
}
__device__ __forceinline__ float bf2f(unsigned short s) {
  return __uint_as_float(((unsigned)s) << 16);
}

// ---------------------------------------------------------------------------
// h = bf16(x @ Wl + bl)
// ---------------------------------------------------------------------------
__global__ __launch_bounds__(256) void node_linear_mfma(
    const float* __restrict__ x, const float* __restrict__ Wl,
    const float* __restrict__ bl, unsigned short* __restrict__ hbf) {
  __shared__ __align__(16) char pool[IN_CH * W2_STR * 2];  // 34816 B
  const int t = threadIdx.x;
  const int lane = t & 63;
  const int l31 = lane & 31;
  const int lhalf = lane >> 5;
  const int wv = t >> 6;

  {
    unsigned short* sWT = (unsigned short*)pool;
    const int k2 = t >> 1;
    const int d0 = (t & 1) * 64;
#pragma unroll
    for (int i = 0; i < 16; ++i) {
      float4 v = *(const float4*)(Wl + k2 * OUT_CH + d0 + 4 * i);
      sWT[(d0 + 4 * i + 0) * W2_STR + k2] = f2bf(v.x);
      sWT[(d0 + 4 * i + 1) * W2_STR + k2] = f2bf(v.y);
      sWT[(d0 + 4 * i + 2) * W2_STR + k2] = f2bf(v.z);
      sWT[(d0 + 4 * i + 3) * W2_STR + k2] = f2bf(v.w);
    }
  }
  __syncthreads();
  const int nbase = wv * 32 + l31;
  bf16x8 BW[8];
  {
    const unsigned short* sWT = (const unsigned short*)pool;
#pragma unroll
    for (int kk = 0; kk < 8; ++kk)
      BW[kk] = *(const bf16x8*)&sWT[nbase * W2_STR + kk * 16 + lhalf * 8];
  }
  const float blv = bl[nbase];
  __syncthreads();

  const int rbase = blockIdx.x * TILE_M;
  unsigned short* sX = (unsigned short*)pool;
  {
    const int m = t >> 2;
    const int c0 = (t & 3) * 32;
    const float* src = x + (size_t)(rbase + m) * IN_CH + c0;
#pragma unroll
    for (int i = 0; i < 8; ++i) {
      float4 v = *(const float4*)(src + 4 * i);
      ushort4 p;
      p.x = f2bf(v.x); p.y = f2bf(v.y); p.z = f2bf(v.z); p.w = f2bf(v.w);
      *(ushort4*)&sX[m * T_STR + c0 + 4 * i] = p;
    }
  }
  __syncthreads();
#pragma unroll
  for (int mt = 0; mt < 2; ++mt) {
    f32x16 acc = {0.f, 0.f, 0.f, 0.f, 0.f, 0.f, 0.f, 0.f,
                  0.f, 0.f, 0.f, 0.f, 0.f, 0.f, 0.f, 0.f};
#pragma unroll
    for (int kk = 0; kk < 8; ++kk) {
      bf16x8 A = *(const bf16x8*)&sX[(mt * 32 + l31) * T_STR + kk * 16 + lhalf * 8];
      acc = __builtin_amdgcn_mfma_f32_32x32x16_bf16(A, BW[kk], acc, 0, 0, 0);
    }
#pragma unroll
    for (int r = 0; r < 16; ++r) {
      const int rowm = mt * 32 + (r & 3) + 8 * (r >> 2) + 4 * lhalf;
      hbf[(size_t)(rbase + rowm) * OUT_CH + nbase] = f2bf(acc[r] + blv);
    }
  }
}

// ---------------------------------------------------------------------------
// counting sort by dst -> spos, row_ptr (hist + hierarchical scan + scatter)
// ---------------------------------------------------------------------------
__global__ void hist_kernel(const int* __restrict__ rowI, int* __restrict__ count) {
  int e = blockIdx.x * 256 + threadIdx.x;
  if (e < N_EDGES) atomicAdd(&count[rowI[e]], 1);
}

__global__ __launch_bounds__(256) void scan1_kernel(const int* __restrict__ count,
                                                    int* __restrict__ tscan,
                                                    int* __restrict__ bsum) {
  __shared__ int s[256];
  const int t = threadIdx.x;
  const int i = blockIdx.x * 256 + t;
  const int v = (i < N_NODES) ? count[i] : 0;
  s[t] = v;
  __syncthreads();
  for (int off = 1; off < 256; off <<= 1) {
    int u = (t >= off) ? s[t - off] : 0;
    __syncthreads();
    s[t] += u;
    __syncthreads();
  }
  if (i < N_NODES) tscan[i] = s[t];
  if (t == 255) bsum[blockIdx.x] = s[255];
}

__global__ __launch_bounds__(256) void scan2_kernel(const int* __restrict__ bsum,
                                                    int* __restrict__ boff) {
  __shared__ int s[256];
  const int t = threadIdx.x;
  const int v = (t < NSCB) ? bsum[t] : 0;
  s[t] = v;
  __syncthreads();
  for (int off = 1; off < 256; off <<= 1) {
    int u = (t >= off) ? s[t - off] : 0;
    __syncthreads();
    s[t] += u;
    __syncthreads();
  }
  if (t < NSCB) boff[t] = s[t] - v;  // exclusive
}

__global__ __launch_bounds__(256) void scan3_kernel(
    const int* __restrict__ count, const int* __restrict__ tscan,
    const int* __restrict__ boff, int* __restrict__ cursor,
    int* __restrict__ row_ptr) {
  const int i = blockIdx.x * 256 + threadIdx.x;
  if (i < N_NODES) {
    const int ex = boff[blockIdx.x] + tscan[i] - count[i];
    cursor[i] = ex;
    row_ptr[i] = ex;
  }
  if (i == 0) row_ptr[N_NODES] = N_EDGES;
}

__global__ void scatter_kernel(const int* __restrict__ rowI, int* __restrict__ cursor,
                               int* __restrict__ spos) {
  int e = blockIdx.x * 256 + threadIdx.x;
  if (e < N_EDGES) spos[e] = atomicAdd(&cursor[rowI[e]], 1);
}

// ---------------------------------------------------------------------------
// Pass A: filter + modulate, natural edge order.
//   ATOMIC=false: scatter-store bf16 msg rows to sorted positions (aux=spos)
//   ATOMIC=true : atomicAdd fp32 into out (aux=rowI), fallback
// ---------------------------------------------------------------------------
template <bool ATOMIC>
__global__ __launch_bounds__(256, 3) void edge_filter_kernel(
    const int* __restrict__ eidx, const float* __restrict__ rbf,
    const float* __restrict__ W1, const float* __restrict__ b1,
    const float* __restrict__ W2, const float* __restrict__ b2,
    const unsigned short* __restrict__ hbf, const int* __restrict__ aux,
    unsigned short* __restrict__ msg, float* __restrict__ outp) {
  __shared__ __align__(16) char pool[IN_CH * W2_STR * 2];           // 34816 B
  __shared__ __align__(16) unsigned short sHv[TILE_M * HV_STR];     // 17408 B
  __shared__ int sAux[TILE_M];

  unsigned short* sT = (unsigned short*)pool;                           // 17408 B
  unsigned short* sRbf = (unsigned short*)(pool + TILE_M * T_STR * 2);  // 9216 B
  unsigned short* sMsg = (unsigned short*)(pool + TILE_M * T_STR * 2);  // 17408 B (after GEMM1)

  const int t = threadIdx.x;
  const int lane = t & 63;
  const int l31 = lane & 31;
  const int lhalf = lane >> 5;
  const int wv = t >> 6;
  const int nbase = wv * 32 + l31;

  // ---- weight fragments (pool reused twice) ----
  {
    unsigned short* sW1T = (unsigned short*)pool;
    const int k = t >> 2;
    const int c0 = (t & 3) * 32;
#pragma unroll
    for (int i = 0; i < 8; ++i) {
      float4 v = *(const float4*)(W1 + k * OUT_CH + c0 + 4 * i);
      sW1T[(c0 + 4 * i + 0) * W1_STR + k] = f2bf(v.x);
      sW1T[(c0 + 4 * i + 1) * W1_STR + k] = f2bf(v.y);
      sW1T[(c0 + 4 * i + 2) * W1_STR + k] = f2bf(v.z);
      sW1T[(c0 + 4 * i + 3) * W1_STR + k] = f2bf(v.w);
    }
  }
  __syncthreads();
  bf16x8 B1[4];
  {
    const unsigned short* sW1T = (const unsigned short*)pool;
#pragma unroll
    for (int kk = 0; kk < 4; ++kk)
      B1[kk] = *(const bf16x8*)&sW1T[nbase * W1_STR + kk * 16 + lhalf * 8];
  }
  __syncthreads();
  {
    unsigned short* sW2T = (unsigned short*)pool;
    const int k2 = t >> 1;
    const int d0 = (t & 1) * 64;
#pragma unroll
    for (int i = 0; i < 16; ++i) {
      float4 v = *(const float4*)(W2 + k2 * OUT_CH + d0 + 4 * i);
      sW2T[(d0 + 4 * i + 0) * W2_STR + k2] = f2bf(v.x);
      sW2T[(d0 + 4 * i + 1) * W2_STR + k2] = f2bf(v.y);
      sW2T[(d0 + 4 * i + 2) * W2_STR + k2] = f2bf(v.z);
      sW2T[(d0 + 4 * i + 3) * W2_STR + k2] = f2bf(v.w);
    }
  }
  __syncthreads();
  bf16x8 B2[8];
  {
    const unsigned short* sW2T = (const unsigned short*)pool;
#pragma unroll
    for (int kk = 0; kk < 8; ++kk)
      B2[kk] = *(const bf16x8*)&sW2T[nbase * W2_STR + kk * 16 + lhalf * 8];
  }
  const float b1v = b1[nbase];
  const float b2v = b2[nbase];

  const int* colI = eidx + N_EDGES;

  for (int tile = blockIdx.x; tile < NTILES; tile += gridDim.x) {
    const int ebase = tile * TILE_M;
    __syncthreads();  // (a) prev scatter-store (sMsg/sAux/sHv reads) complete

    // ---- stage rbf (bf16) + hbf rows -> sHv (16B chunks) + aux ----
    {
      const int m = t >> 2;
      const int kq = (t & 3) * 16;
      const float* src = rbf + (size_t)(ebase + m) * NUM_RBF + kq;
#pragma unroll
      for (int i = 0; i < 4; ++i) {
        float4 v = *(const float4*)(src + 4 * i);
        ushort4 p;
        p.x = f2bf(v.x); p.y = f2bf(v.y); p.z = f2bf(v.z); p.w = f2bf(v.w);
        *(ushort4*)&sRbf[m * RBF_STR + kq + 4 * i] = p;
      }
      // 64 rows x 256B of hbf, 16B per thread-chunk, 4 chunks/thread
#pragma unroll
      for (int i = 0; i < 4; ++i) {
        const int chunk = t + 256 * i;
        const int row = chunk >> 4;
        const int c8 = (chunk & 15) * 8;  // ushort offset within row
        const int col = colI[ebase + row];
        *(uint4*)&sHv[row * HV_STR + c8] =
            *(const uint4*)(hbf + (size_t)col * OUT_CH + c8);
      }
      if (t < TILE_M) sAux[t] = aux[ebase + t];
    }
    __syncthreads();  // (b)

    // ---- GEMM1: sT = bf16(relu(rbf @ W1 + b1)) ----
#pragma unroll
    for (int mt = 0; mt < 2; ++mt) {
      f32x16 acc = {0.f, 0.f, 0.f, 0.f, 0.f, 0.f, 0.f, 0.f,
                    0.f, 0.f, 0.f, 0.f, 0.f, 0.f, 0.f, 0.f};
#pragma unroll
      for (int kk = 0; kk < 4; ++kk) {
        bf16x8 A = *(const bf16x8*)&sRbf[(mt * 32 + l31) * RBF_STR + kk * 16 + lhalf * 8];
        acc = __builtin_amdgcn_mfma_f32_32x32x16_bf16(A, B1[kk], acc, 0, 0, 0);
      }
#pragma unroll
      for (int r = 0; r < 16; ++r) {
        const int rowm = (r & 3) + 8 * (r >> 2) + 4 * lhalf;
        float v = acc[r] + b1v;
        v = v > 0.f ? v : 0.f;
        sT[(mt * 32 + rowm) * T_STR + nbase] = f2bf(v);
      }
    }
    __syncthreads();  // (c) sRbf dead; sMsg may reuse its space

    // ---- h values from LDS (2-way banks, conflict-free) ----
    float hv[2][16];
#pragma unroll
    for (int mt = 0; mt < 2; ++mt)
#pragma unroll
      for (int r = 0; r < 16; ++r) {
        const int rowm = mt * 32 + (r & 3) + 8 * (r >> 2) + 4 * lhalf;
        hv[mt][r] = bf2f(sHv[rowm * HV_STR + nbase]);
      }

    // ---- GEMM2 + modulate ----
#pragma unroll
    for (int mt = 0; mt < 2; ++mt) {
      f32x16 acc = {0.f, 0.f, 0.f, 0.f, 0.f, 0.f, 0.f, 0.f,
                    0.f, 0.f, 0.f, 0.f, 0.f, 0.f, 0.f, 0.f};
#pragma unroll
      for (int kk = 0; kk < 8; ++kk) {
        bf16x8 A = *(const bf16x8*)&sT[(mt * 32 + l31) * T_STR + kk * 16 + lhalf * 8];
        acc = __builtin_amdgcn_mfma_f32_32x32x16_bf16(A, B2[kk], acc, 0, 0, 0);
      }
#pragma unroll
      for (int r = 0; r < 16; ++r) {
        const int rowm = mt * 32 + (r & 3) + 8 * (r >> 2) + 4 * lhalf;
        const float m = hv[mt][r] * (acc[r] + b2v);
        if (ATOMIC) {
          atomicAdd(&outp[(size_t)sAux[rowm] * OUT_CH + nbase], m);
        } else {
          sMsg[rowm * T_STR + nbase] = f2bf(m);
        }
      }
    }

    if (!ATOMIC) {
      __syncthreads();  // (d) sMsg complete
      const int m = t >> 2;
      unsigned short* dst = msg + (size_t)sAux[m] * OUT_CH;
#pragma unroll
      for (int i = 0; i < 4; ++i) {
        const int j = ((t & 3) * 4 + i) * 8;  // ushort offset, 16B chunk
        *(ushort4*)(dst + j) = *(const ushort4*)&sMsg[m * T_STR + j];
        *(ushort4*)(dst + j + 4) = *(const ushort4*)&sMsg[m * T_STR + j + 4];
      }
    }
  }
}

// ---------------------------------------------------------------------------
// Pass B: per-node contiguous segment reduce. One wave per node.
// ---------------------------------------------------------------------------
__global__ __launch_bounds__(256) void segment_reduce_kernel(
    const unsigned short* __restrict__ msg, const int* __restrict__ row_ptr,
    float* __restrict__ out) {
  const int t = threadIdx.x;
  const int wv = t >> 6;
  const int lane = t & 63;
  const int n = blockIdx.x * 4 + wv;
  const int ebeg = row_ptr[n];
  const int eend = row_ptr[n + 1];
  const unsigned* p = (const unsigned*)msg;  // row = 64 uints (128 bf16)

  float a0 = 0.f, a1 = 0.f;
  int e = ebeg;
  for (; e + 4 <= eend; e += 4) {
    unsigned v0 = p[(size_t)(e + 0) * 64 + lane];
    unsigned v1 = p[(size_t)(e + 1) * 64 + lane];
    unsigned v2 = p[(size_t)(e + 2) * 64 + lane];
    unsigned v3 = p[(size_t)(e + 3) * 64 + lane];
    a0 += bf2f((unsigned short)(v0 & 0xffff)) + bf2f((unsigned short)(v1 & 0xffff)) +
          bf2f((unsigned short)(v2 & 0xffff)) + bf2f((unsigned short)(v3 & 0xffff));
    a1 += bf2f((unsigned short)(v0 >> 16)) + bf2f((unsigned short)(v1 >> 16)) +
          bf2f((unsigned short)(v2 >> 16)) + bf2f((unsigned short)(v3 >> 16));
  }
  for (; e < eend; ++e) {
    unsigned v = p[(size_t)e * 64 + lane];
    a0 += bf2f((unsigned short)(v & 0xffff));
    a1 += bf2f((unsigned short)(v >> 16));
  }
  float2 r;
  r.x = a0;
  r.y = a1;
  *(float2*)&out[(size_t)n * OUT_CH + lane * 2] = r;
}

// ---------------------------------------------------------------------------
extern "C" void kernel_launch(void* const* d_in, const int* in_sizes, int n_in,
                              void* d_out, int out_size, void* d_ws, size_t ws_size,
                              hipStream_t stream) {
  const float* x    = (const float*)d_in[0];
  const int*   eidx = (const int*)d_in[1];
  const float* rbf  = (const float*)d_in[2];
  const float* W1   = (const float*)d_in[3];
  const float* b1   = (const float*)d_in[4];
  const float* W2   = (const float*)d_in[5];
  const float* b2   = (const float*)d_in[6];
  const float* Wl   = (const float*)d_in[7];
  const float* bl   = (const float*)d_in[8];
  float* out = (float*)d_out;

  char* ws = (char*)d_ws;
  const size_t HBF_B = (size_t)N_NODES * OUT_CH * 2;       // 10,240,000
  const size_t MSG_B = (size_t)N_EDGES * OUT_CH * 2;       // 163,840,000
  const size_t SPOS_B = (size_t)N_EDGES * 4;               //   2,560,000
  const size_t CNT_B = (size_t)N_NODES * 4;                //     160,000
  const size_t RP_B = CNT_B + 64;
  const size_t BS_B = 4 * 256;
  const size_t need =
      HBF_B + MSG_B + SPOS_B + CNT_B * 3 + RP_B + 2 * BS_B + 64;

  size_t off = 0;
  unsigned short* hbf = (unsigned short*)(ws + off); off += HBF_B;
  unsigned short* msg = (unsigned short*)(ws + off); off += MSG_B;
  int* spos    = (int*)(ws + off); off += SPOS_B;
  int* count   = (int*)(ws + off); off += CNT_B;
  int* cursor  = (int*)(ws + off); off += CNT_B;
  int* tscan   = (int*)(ws + off); off += CNT_B;
  int* row_ptr = (int*)(ws + off); off += RP_B;
  int* bsum    = (int*)(ws + off); off += BS_B;
  int* boff    = (int*)(ws + off); off += BS_B;

  node_linear_mfma<<<N_NODES / TILE_M, 256, 0, stream>>>(x, Wl, bl, hbf);

  if (ws_size >= need) {
    hipMemsetAsync(count, 0, CNT_B, stream);
    hist_kernel<<<(N_EDGES + 255) / 256, 256, 0, stream>>>(eidx, count);
    scan1_kernel<<<NSCB, 256, 0, stream>>>(count, tscan, bsum);
    scan2_kernel<<<1, 256, 0, stream>>>(bsum, boff);
    scan3_kernel<<<NSCB, 256, 0, stream>>>(count, tscan, boff, cursor, row_ptr);
    scatter_kernel<<<(N_EDGES + 255) / 256, 256, 0, stream>>>(eidx, cursor, spos);
    edge_filter_kernel<false><<<2500, 256, 0, stream>>>(
        eidx, rbf, W1, b1, W2, b2, hbf, spos, msg, nullptr);
    segment_reduce_kernel<<<N_NODES / 4, 256, 0, stream>>>(msg, row_ptr, out);
  } else {
    hipMemsetAsync(out, 0, (size_t)N_NODES * OUT_CH * sizeof(float), stream);
    edge_filter_kernel<true><<<2500, 256, 0, stream>>>(
        eidx, rbf, W1, b1, W2, b2, hbf, eidx /*rowI*/, nullptr, out);
  }
}